// Round 1
// baseline (1206.870 us; speedup 1.0000x reference)
//
#include <hip/hip_runtime.h>

#define HH 64
#define EAD 16
#define NLAYERS 5

// ---------------- setup kernels ----------------
__global__ void k_deg_hist(const int* ei, int E, int* deg) {
    int i = blockIdx.x * blockDim.x + threadIdx.x;
    int stride = gridDim.x * blockDim.x;
    for (int e = i; e < E; e += stride) {
        int s = ei[e], d = ei[E + e];
        if (s != d) atomicAdd(&deg[d], 1);
    }
}

__global__ void k_cnt_hist(const int* batch, int N, int* cnt) {
    int i = blockIdx.x * blockDim.x + threadIdx.x;
    int stride = gridDim.x * blockDim.x;
    for (int n = i; n < N; n += stride) atomicAdd(&cnt[batch[n]], 1);
}

__global__ void k_scan(const int* deg, int N, int* rowptr, int* cursor) {
    __shared__ int ps[1024];
    int tid = threadIdx.x;
    int chunk = (N + 1023) >> 10;
    int s = 0;
    for (int i = 0; i < chunk; i++) {
        int idx = tid * chunk + i;
        if (idx < N) s += deg[idx];
    }
    ps[tid] = s;
    __syncthreads();
    for (int off = 1; off < 1024; off <<= 1) {
        int v = (tid >= off) ? ps[tid - off] : 0;
        __syncthreads();
        ps[tid] += v;
        __syncthreads();
    }
    int run = (tid == 0) ? 0 : ps[tid - 1];
    for (int i = 0; i < chunk; i++) {
        int idx = tid * chunk + i;
        if (idx < N) { rowptr[idx] = run; cursor[idx] = run; run += deg[idx]; }
    }
    if (tid == 1023) rowptr[N] = ps[1023];
}

__global__ void k_scatter(const int* ei, int E, int* cursor, int* csr_src, int* csr_eid) {
    int i = blockIdx.x * blockDim.x + threadIdx.x;
    int stride = gridDim.x * blockDim.x;
    for (int e = i; e < E; e += stride) {
        int s = ei[e], d = ei[E + e];
        if (s != d) {
            int pos = atomicAdd(&cursor[d], 1);
            csr_src[pos] = s;
            csr_eid[pos] = e;
        }
    }
}

// Precompute fused 64x64 matrices:
//  job 0..4 : P[l]  = nn2_w2[l] @ nn1_w1[l],  pb[l] = nn2_b2[l] @ nn1_w1[l]
//  job 5..8 : Q[l]  = nn1_w2[l] @ Wx[l+1],    qb[l] = nn1_b2[l] @ Wx[l+1]
//  job 9..12: R[l]  = nn1_w2[l] @ nn1_w1[l+1],rb[l] = nn1_b2[l] @ nn1_w1[l+1]
__global__ void k_precompute(const float* nn2_w1, const float* nn2_w2, const float* nn2_b2,
                             const float* nn1_w1, const float* nn1_w2, const float* nn1_b2,
                             float* P, float* pb, float* Q, float* qb, float* R, float* rb) {
    int job = blockIdx.x;
    const float* left; const float* lb; const float* right; float* out; float* ob;
    if (job < 5) {
        int l = job;
        left = nn2_w2 + l * 4096; lb = nn2_b2 + l * 64; right = nn1_w1 + l * 4096;
        out = P + l * 4096; ob = pb + l * 64;
    } else if (job < 9) {
        int l = job - 5;
        left = nn1_w2 + l * 4096; lb = nn1_b2 + l * 64; right = nn2_w1 + (l + 1) * 5120;
        out = Q + l * 4096; ob = qb + l * 64;
    } else {
        int l = job - 9;
        left = nn1_w2 + l * 4096; lb = nn1_b2 + l * 64; right = nn1_w1 + (l + 1) * 4096;
        out = R + l * 4096; ob = rb + l * 64;
    }
    int t = threadIdx.x;
    int r0 = (t >> 4) * 4, c0 = (t & 15) * 4;
    float acc[4][4] = {};
    for (int k = 0; k < 64; k++) {
        float b[4];
        #pragma unroll
        for (int j = 0; j < 4; j++) b[j] = right[k * 64 + c0 + j];
        #pragma unroll
        for (int i = 0; i < 4; i++) {
            float a = left[(r0 + i) * 64 + k];
            #pragma unroll
            for (int j = 0; j < 4; j++) acc[i][j] += a * b[j];
        }
    }
    for (int i = 0; i < 4; i++)
        for (int j = 0; j < 4; j++)
            out[(r0 + i) * 64 + c0 + j] = acc[i][j];
    if (t < 64) {
        float s = 0.f;
        for (int k = 0; k < 64; k++) s += lb[k] * right[k * 64 + t];
        ob[t] = s;
    }
}

// 4x4 micro-tile GEMM over a 64x64 tile; AT is transposed A in LDS (stride 68), W row-major in LDS.
__device__ __forceinline__ void gemm_tile(const float* AT, const float* W, float acc[4][4], int ty, int tx) {
    #pragma unroll
    for (int i = 0; i < 4; i++)
        #pragma unroll
        for (int j = 0; j < 4; j++) acc[i][j] = 0.f;
    #pragma unroll 4
    for (int k = 0; k < 64; k++) {
        const float4 a4 = *(const float4*)(AT + k * 68 + ty * 4);
        const float4 b4 = *(const float4*)(W + k * 64 + tx * 4);
        float a[4] = {a4.x, a4.y, a4.z, a4.w};
        float b[4] = {b4.x, b4.y, b4.z, b4.w};
        #pragma unroll
        for (int i = 0; i < 4; i++)
            #pragma unroll
            for (int j = 0; j < 4; j++) acc[i][j] += a[i] * b[j];
    }
}

// out1 = X @ M1, out2 = X @ M2  (no bias) — used for layer 0: xW1 = x@Wx0, xA = x@A0
__global__ void k_gemm_two(const float* __restrict__ X, const float* __restrict__ M1,
                           const float* __restrict__ M2, float* __restrict__ out1,
                           float* __restrict__ out2, int N) {
    __shared__ float XT[64 * 68];
    __shared__ float W[64 * 64];
    int t = threadIdx.x, ty = t >> 4, tx = t & 15;
    int base = blockIdx.x * 64;
    for (int q = 0; q < 4; q++) {
        int row = ty + q * 16;
        int gr = base + row;
        float4 v = make_float4(0.f, 0.f, 0.f, 0.f);
        if (gr < N) v = *(const float4*)(X + (size_t)gr * 64 + tx * 4);
        XT[(tx * 4 + 0) * 68 + row] = v.x;
        XT[(tx * 4 + 1) * 68 + row] = v.y;
        XT[(tx * 4 + 2) * 68 + row] = v.z;
        XT[(tx * 4 + 3) * 68 + row] = v.w;
    }
    for (int q = 0; q < 4; q++) ((float4*)W)[t + q * 256] = ((const float4*)M1)[t + q * 256];
    __syncthreads();
    float acc[4][4];
    gemm_tile(XT, W, acc, ty, tx);
    for (int i = 0; i < 4; i++) {
        int gr = base + ty * 4 + i;
        if (gr < N) {
            float4 o = make_float4(acc[i][0], acc[i][1], acc[i][2], acc[i][3]);
            *(float4*)(out1 + (size_t)gr * 64 + tx * 4) = o;
        }
    }
    __syncthreads();
    for (int q = 0; q < 4; q++) ((float4*)W)[t + q * 256] = ((const float4*)M2)[t + q * 256];
    __syncthreads();
    gemm_tile(XT, W, acc, ty, tx);
    for (int i = 0; i < 4; i++) {
        int gr = base + ty * 4 + i;
        if (gr < N) {
            float4 o = make_float4(acc[i][0], acc[i][1], acc[i][2], acc[i][3]);
            *(float4*)(out2 + (size_t)gr * 64 + tx * 4) = o;
        }
    }
}

// Edge phase: one wave per destination node. Hsum[d][c] = sum over in-edges ReLU(xW1[s][c] + ea@We[:,c] + b1[c])
__global__ void k_edge(const int* __restrict__ rowptr, const int* __restrict__ csr_src,
                       const int* __restrict__ csr_eid, const float* __restrict__ edge_attr,
                       const float* __restrict__ xW1, const float* __restrict__ We,
                       const float* __restrict__ b1m, float* __restrict__ Hsum, int N) {
    int wid = (blockIdx.x * blockDim.x + threadIdx.x) >> 6;
    int lane = threadIdx.x & 63;
    if (wid >= N) return;
    float wcol[16];
    #pragma unroll
    for (int k = 0; k < 16; k++) wcol[k] = We[k * 64 + lane];
    float b1 = b1m[lane];
    int beg = rowptr[wid], end = rowptr[wid + 1];
    float acc = 0.f;
    for (int j = beg; j < end; j++) {
        int s = csr_src[j];
        int eid = csr_eid[j];
        float v = xW1[(size_t)s * 64 + lane] + b1;
        const float4* ea = (const float4*)(edge_attr + (size_t)eid * 16);
        float4 e0 = ea[0], e1 = ea[1], e2 = ea[2], e3 = ea[3];
        v += e0.x * wcol[0] + e0.y * wcol[1] + e0.z * wcol[2] + e0.w * wcol[3]
           + e1.x * wcol[4] + e1.y * wcol[5] + e1.z * wcol[6] + e1.w * wcol[7]
           + e2.x * wcol[8] + e2.y * wcol[9] + e2.z * wcol[10] + e2.w * wcol[11]
           + e3.x * wcol[12] + e3.y * wcol[13] + e3.z * wcol[14] + e3.w * wcol[15];
        acc += fmaxf(v, 0.f);
    }
    Hsum[(size_t)wid * 64 + lane] = acc;
}

// Node phase for layer l:
//   h = ReLU( Hsum@P + (1+eps)*xA + deg*pb + a_l )
//   pooled: hpool[batch[n]] += h
//   if has_next: out1 = h@Q + qb  (next xW1), out2 = h@R + rb  (next xA)
__global__ void k_node(const float* __restrict__ Hsum, const float* __restrict__ xA,
                       const int* __restrict__ deg, const int* __restrict__ batch,
                       const float* __restrict__ P, const float* __restrict__ pb,
                       const float* __restrict__ a_l, const float* __restrict__ epsp,
                       const float* __restrict__ Q, const float* __restrict__ qb,
                       float* __restrict__ out1,
                       const float* __restrict__ R, const float* __restrict__ rb,
                       float* __restrict__ out2,
                       float* __restrict__ hpool_l, int N, int has_next) {
    __shared__ float AT[64 * 68];
    __shared__ float HT[64 * 68];
    __shared__ float W[64 * 64];
    int t = threadIdx.x, ty = t >> 4, tx = t & 15;
    int base = blockIdx.x * 64;
    // stage Hsum tile transposed
    for (int q = 0; q < 4; q++) {
        int row = ty + q * 16;
        int gr = base + row;
        float4 v = make_float4(0.f, 0.f, 0.f, 0.f);
        if (gr < N) v = *(const float4*)(Hsum + (size_t)gr * 64 + tx * 4);
        AT[(tx * 4 + 0) * 68 + row] = v.x;
        AT[(tx * 4 + 1) * 68 + row] = v.y;
        AT[(tx * 4 + 2) * 68 + row] = v.z;
        AT[(tx * 4 + 3) * 68 + row] = v.w;
    }
    for (int q = 0; q < 4; q++) ((float4*)W)[t + q * 256] = ((const float4*)P)[t + q * 256];
    __syncthreads();
    float acc[4][4];
    gemm_tile(AT, W, acc, ty, tx);
    float eps1 = 1.f + epsp[0];
    float4 pbv = *(const float4*)(pb + tx * 4);
    float4 av = *(const float4*)(a_l + tx * 4);
    float h[4][4];
    int gidx[4];
    for (int i = 0; i < 4; i++) {
        int gr = base + ty * 4 + i;
        float dg = 0.f;
        float4 xa = make_float4(0.f, 0.f, 0.f, 0.f);
        if (gr < N) {
            dg = (float)deg[gr];
            xa = *(const float4*)(xA + (size_t)gr * 64 + tx * 4);
            gidx[i] = batch[gr];
        } else {
            gidx[i] = -1;
        }
        h[i][0] = fmaxf(acc[i][0] + eps1 * xa.x + dg * pbv.x + av.x, 0.f);
        h[i][1] = fmaxf(acc[i][1] + eps1 * xa.y + dg * pbv.y + av.y, 0.f);
        h[i][2] = fmaxf(acc[i][2] + eps1 * xa.z + dg * pbv.z + av.z, 0.f);
        h[i][3] = fmaxf(acc[i][3] + eps1 * xa.w + dg * pbv.w + av.w, 0.f);
    }
    // pooled readout: segment-add consecutive rows with same graph id
    #pragma unroll
    for (int j = 0; j < 4; j++) {
        int i = 0;
        while (i < 4) {
            if (gidx[i] < 0) { i++; continue; }
            int g = gidx[i];
            float s = h[i][j];
            int k2 = i + 1;
            while (k2 < 4 && gidx[k2] == g) { s += h[k2][j]; k2++; }
            atomicAdd(&hpool_l[g * 64 + tx * 4 + j], s);
            i = k2;
        }
    }
    if (has_next) {
        for (int i = 0; i < 4; i++)
            for (int j = 0; j < 4; j++)
                HT[(tx * 4 + j) * 68 + ty * 4 + i] = h[i][j];
        __syncthreads();
        for (int q = 0; q < 4; q++) ((float4*)W)[t + q * 256] = ((const float4*)Q)[t + q * 256];
        __syncthreads();
        gemm_tile(HT, W, acc, ty, tx);
        float4 qbv = *(const float4*)(qb + tx * 4);
        for (int i = 0; i < 4; i++) {
            int gr = base + ty * 4 + i;
            if (gr < N) {
                float4 o = make_float4(acc[i][0] + qbv.x, acc[i][1] + qbv.y,
                                       acc[i][2] + qbv.z, acc[i][3] + qbv.w);
                *(float4*)(out1 + (size_t)gr * 64 + tx * 4) = o;
            }
        }
        __syncthreads();
        for (int q = 0; q < 4; q++) ((float4*)W)[t + q * 256] = ((const float4*)R)[t + q * 256];
        __syncthreads();
        gemm_tile(HT, W, acc, ty, tx);
        float4 rbv = *(const float4*)(rb + tx * 4);
        for (int i = 0; i < 4; i++) {
            int gr = base + ty * 4 + i;
            if (gr < N) {
                float4 o = make_float4(acc[i][0] + rbv.x, acc[i][1] + rbv.y,
                                       acc[i][2] + rbv.z, acc[i][3] + rbv.w);
                *(float4*)(out2 + (size_t)gr * 64 + tx * 4) = o;
            }
        }
    }
}

// feats[g][l*64+c] = sum_k hpool[l][g][k]*nn1_w2[l][k][c] + cnt[g]*nn1_b2[l][c]
__global__ void k_pool_feats(const float* __restrict__ hpool, const int* __restrict__ cnt,
                             const float* __restrict__ nn1_w2, const float* __restrict__ nn1_b2,
                             float* __restrict__ feats, int G) {
    int l = blockIdx.x / G, g = blockIdx.x % G;
    int c = threadIdx.x;
    const float* hp = hpool + ((size_t)l * G + g) * 64;
    const float* B = nn1_w2 + l * 4096;
    float s = (float)cnt[g] * nn1_b2[l * 64 + c];
    for (int k = 0; k < 64; k++) s += hp[k] * B[k * 64 + c];
    feats[(size_t)g * (64 * NLAYERS) + l * 64 + c] = s;
}

// y[g] = ReLU(feats[g]@F1 + fb1) @ F2 + fb2
__global__ void k_final(const float* __restrict__ feats, const float* __restrict__ F1,
                        const float* __restrict__ fb1, const float* __restrict__ F2,
                        const float* __restrict__ fb2, float* __restrict__ out, int G) {
    int g = blockIdx.x;
    int c = threadIdx.x; // 320
    const float* f = feats + (size_t)g * 320;
    float s = fb1[c];
    for (int k = 0; k < 320; k++) s += f[k] * F1[k * 320 + c];
    s = fmaxf(s, 0.f);
    __shared__ float sh[320];
    sh[c] = s * F2[c];
    __syncthreads();
    if (c == 0) {
        float y = fb2[0];
        for (int k = 0; k < 320; k++) y += sh[k];
        out[g] = y;
    }
}

extern "C" void kernel_launch(void* const* d_in, const int* in_sizes, int n_in,
                              void* d_out, int out_size, void* d_ws, size_t ws_size,
                              hipStream_t stream) {
    const float* x        = (const float*)d_in[0];
    const int*   ei       = (const int*)d_in[1];
    const float* edge_attr= (const float*)d_in[2];
    const int*   batch    = (const int*)d_in[3];
    const float* nn2_w1   = (const float*)d_in[4];
    const float* nn2_b1   = (const float*)d_in[5];
    const float* nn2_w2   = (const float*)d_in[6];
    const float* nn2_b2   = (const float*)d_in[7];
    const float* nn1_w1   = (const float*)d_in[8];
    const float* nn1_b1   = (const float*)d_in[9];
    const float* nn1_w2   = (const float*)d_in[10];
    const float* nn1_b2   = (const float*)d_in[11];
    const float* fin_w1   = (const float*)d_in[12];
    const float* fin_b1   = (const float*)d_in[13];
    const float* fin_w2   = (const float*)d_in[14];
    const float* fin_b2   = (const float*)d_in[15];
    const float* eps      = (const float*)d_in[16];

    int N = in_sizes[0] / 64;
    int E = in_sizes[1] / 2;
    int G = out_size;

    char* p = (char*)d_ws;
    auto alloc = [&](size_t bytes) -> char* {
        char* r = p;
        p += (bytes + 255) & ~(size_t)255;
        return r;
    };
    int*   deg     = (int*)alloc((size_t)N * 4);
    int*   cnt     = (int*)alloc((size_t)G * 4);
    int*   rowptr  = (int*)alloc((size_t)(N + 1) * 4);
    int*   cursor  = (int*)alloc((size_t)(N + 1) * 4);
    int*   csr_src = (int*)alloc((size_t)E * 4);
    int*   csr_eid = (int*)alloc((size_t)E * 4);
    float* xW1     = (float*)alloc((size_t)N * 64 * 4);
    float* xA0     = (float*)alloc((size_t)N * 64 * 4);
    float* xA1     = (float*)alloc((size_t)N * 64 * 4);
    float* Hsum    = (float*)alloc((size_t)N * 64 * 4);
    float* hpool   = (float*)alloc((size_t)NLAYERS * G * 64 * 4);
    float* feats   = (float*)alloc((size_t)G * 320 * 4);
    float* P       = (float*)alloc(5 * 4096 * 4);
    float* pb      = (float*)alloc(5 * 64 * 4);
    float* Q       = (float*)alloc(4 * 4096 * 4);
    float* qb      = (float*)alloc(4 * 64 * 4);
    float* R       = (float*)alloc(4 * 4096 * 4);
    float* rb      = (float*)alloc(4 * 64 * 4);

    hipMemsetAsync(deg, 0, (size_t)N * 4, stream);
    hipMemsetAsync(cnt, 0, (size_t)G * 4, stream);
    hipMemsetAsync(hpool, 0, (size_t)NLAYERS * G * 64 * 4, stream);

    k_deg_hist<<<1024, 256, 0, stream>>>(ei, E, deg);
    k_cnt_hist<<<256, 256, 0, stream>>>(batch, N, cnt);
    k_scan<<<1, 1024, 0, stream>>>(deg, N, rowptr, cursor);
    k_scatter<<<1024, 256, 0, stream>>>(ei, E, cursor, csr_src, csr_eid);
    k_precompute<<<13, 256, 0, stream>>>(nn2_w1, nn2_w2, nn2_b2, nn1_w1, nn1_w2, nn1_b2,
                                         P, pb, Q, qb, R, rb);

    int nb = (N + 63) / 64;
    k_gemm_two<<<nb, 256, 0, stream>>>(x, nn2_w1 /*Wx0*/, nn1_w1 /*A0*/, xW1, xA0, N);

    float* xA_cur = xA0;
    float* xA_nxt = xA1;
    int eblocks = (N + 3) / 4; // 4 waves per 256-thread block, one wave per node
    for (int l = 0; l < NLAYERS; l++) {
        k_edge<<<eblocks, 256, 0, stream>>>(rowptr, csr_src, csr_eid, edge_attr, xW1,
                                            nn2_w1 + l * 5120 + 4096, nn2_b1 + l * 64, Hsum, N);
        int has_next = (l < NLAYERS - 1) ? 1 : 0;
        k_node<<<nb, 256, 0, stream>>>(Hsum, xA_cur, deg, batch,
                                       P + l * 4096, pb + l * 64, nn1_b1 + l * 64, eps,
                                       Q + (has_next ? l : 0) * 4096, qb + (has_next ? l : 0) * 64, xW1,
                                       R + (has_next ? l : 0) * 4096, rb + (has_next ? l : 0) * 64, xA_nxt,
                                       hpool + (size_t)l * G * 64, N, has_next);
        float* tmp = xA_cur; xA_cur = xA_nxt; xA_nxt = tmp;
    }

    k_pool_feats<<<NLAYERS * G, 64, 0, stream>>>(hpool, cnt, nn1_w2, nn1_b2, feats, G);
    k_final<<<G, 320, 0, stream>>>(feats, fin_w1, fin_b1, fin_w2, fin_b2, (float*)d_out, G);
}

// Round 2
// 703.750 us; speedup vs baseline: 1.7149x; 1.7149x over previous
//
#include <hip/hip_runtime.h>
#include <hip/hip_fp16.h>

#define HH 64
#define EAD 16
#define NLAYERS 5

struct alignas(8) H4 { __half h[4]; };

// ---------------- setup kernels ----------------
__global__ void k_deg_hist(const int* ei, int E, int* deg) {
    int i = blockIdx.x * blockDim.x + threadIdx.x;
    int stride = gridDim.x * blockDim.x;
    for (int e = i; e < E; e += stride) {
        int s = ei[e], d = ei[E + e];
        if (s != d) atomicAdd(&deg[d], 1);
    }
}

__global__ void k_cnt_hist(const int* batch, int N, int* cnt) {
    int i = blockIdx.x * blockDim.x + threadIdx.x;
    int stride = gridDim.x * blockDim.x;
    for (int n = i; n < N; n += stride) atomicAdd(&cnt[batch[n]], 1);
}

// hierarchical scan: bsum (per-256-node block sums) -> bscan (1 block) -> rowptr
__global__ void k_bsum(const int* __restrict__ deg, int N, int* __restrict__ bsum) {
    __shared__ int sh[256];
    int t = threadIdx.x, i = blockIdx.x * 256 + t;
    sh[t] = (i < N) ? deg[i] : 0;
    __syncthreads();
    for (int o = 128; o > 0; o >>= 1) {
        if (t < o) sh[t] += sh[t + o];
        __syncthreads();
    }
    if (t == 0) bsum[blockIdx.x] = sh[0];
}

__global__ void k_bscan(const int* __restrict__ bsum, int P, int* __restrict__ boff,
                        int* __restrict__ rowptr, int N) {
    __shared__ int sh[256];
    int t = threadIdx.x;
    int v = (t < P) ? bsum[t] : 0;
    sh[t] = v;
    __syncthreads();
    for (int o = 1; o < 256; o <<= 1) {
        int u = (t >= o) ? sh[t - o] : 0;
        __syncthreads();
        sh[t] += u;
        __syncthreads();
    }
    if (t < P) boff[t] = sh[t] - v;      // exclusive
    if (t == 255) rowptr[N] = sh[255];   // total edges (non-self)
}

__global__ void k_rowptr(const int* __restrict__ deg, const int* __restrict__ boff, int N,
                         int* __restrict__ rowptr, int* __restrict__ cursor) {
    __shared__ int sh[256];
    int t = threadIdx.x, i = blockIdx.x * 256 + t;
    int v = (i < N) ? deg[i] : 0;
    sh[t] = v;
    __syncthreads();
    for (int o = 1; o < 256; o <<= 1) {
        int u = (t >= o) ? sh[t - o] : 0;
        __syncthreads();
        sh[t] += u;
        __syncthreads();
    }
    int ex = sh[t] - v + boff[blockIdx.x];
    if (i < N) { rowptr[i] = ex; cursor[i] = ex; }
}

// scatter + fused edge_attr f16 permute into CSR order (eliminates per-layer eid gather)
__global__ void k_scatter(const int* __restrict__ ei, const float* __restrict__ edge_attr,
                          int E, int* __restrict__ cursor, int* __restrict__ csr_src,
                          __half* __restrict__ eaPerm) {
    int i = blockIdx.x * blockDim.x + threadIdx.x;
    int stride = gridDim.x * blockDim.x;
    for (int e = i; e < E; e += stride) {
        int s = ei[e], d = ei[E + e];
        if (s != d) {
            int pos = atomicAdd(&cursor[d], 1);
            csr_src[pos] = s;
            const float4* ea4 = (const float4*)(edge_attr + (size_t)e * 16);
            float4 a = ea4[0], b = ea4[1], c = ea4[2], dd = ea4[3];
            union { __half h[8]; float4 f; } u0, u1;
            u0.h[0] = __float2half(a.x); u0.h[1] = __float2half(a.y);
            u0.h[2] = __float2half(a.z); u0.h[3] = __float2half(a.w);
            u0.h[4] = __float2half(b.x); u0.h[5] = __float2half(b.y);
            u0.h[6] = __float2half(b.z); u0.h[7] = __float2half(b.w);
            u1.h[0] = __float2half(c.x); u1.h[1] = __float2half(c.y);
            u1.h[2] = __float2half(c.z); u1.h[3] = __float2half(c.w);
            u1.h[4] = __float2half(dd.x); u1.h[5] = __float2half(dd.y);
            u1.h[6] = __float2half(dd.z); u1.h[7] = __float2half(dd.w);
            float4* out = (float4*)(eaPerm + (size_t)pos * 16);
            out[0] = u0.f; out[1] = u1.f;
        }
    }
}

// pack We (rows 64..79 of nn2_w1[l]) into half2 pairs: Wpack[l][p][lane] = (We[2p][lane], We[2p+1][lane])
__global__ void k_wpack(const float* __restrict__ nn2_w1, __half2* __restrict__ Wpack) {
    int l = blockIdx.x, t = threadIdx.x; // 512 threads: p = t>>6, lane = t&63
    int p = t >> 6, lane = t & 63;
    const float* W = nn2_w1 + (size_t)l * 5120 + 64 * 64;
    float a = W[(2 * p) * 64 + lane];
    float b = W[(2 * p + 1) * 64 + lane];
    Wpack[l * 512 + t] = __halves2half2(__float2half(a), __float2half(b));
}

// Precompute fused 64x64 matrices:
//  job 0..4 : P[l]  = nn2_w2[l] @ nn1_w1[l],  pb[l] = nn2_b2[l] @ nn1_w1[l]
//  job 5..8 : Q[l]  = nn1_w2[l] @ Wx[l+1],    qb[l] = nn1_b2[l] @ Wx[l+1]
//  job 9..12: R[l]  = nn1_w2[l] @ nn1_w1[l+1],rb[l] = nn1_b2[l] @ nn1_w1[l+1]
__global__ void k_precompute(const float* nn2_w1, const float* nn2_w2, const float* nn2_b2,
                             const float* nn1_w1, const float* nn1_w2, const float* nn1_b2,
                             float* P, float* pb, float* Q, float* qb, float* R, float* rb) {
    int job = blockIdx.x;
    const float* left; const float* lb; const float* right; float* out; float* ob;
    if (job < 5) {
        int l = job;
        left = nn2_w2 + l * 4096; lb = nn2_b2 + l * 64; right = nn1_w1 + l * 4096;
        out = P + l * 4096; ob = pb + l * 64;
    } else if (job < 9) {
        int l = job - 5;
        left = nn1_w2 + l * 4096; lb = nn1_b2 + l * 64; right = nn2_w1 + (l + 1) * 5120;
        out = Q + l * 4096; ob = qb + l * 64;
    } else {
        int l = job - 9;
        left = nn1_w2 + l * 4096; lb = nn1_b2 + l * 64; right = nn1_w1 + (l + 1) * 4096;
        out = R + l * 4096; ob = rb + l * 64;
    }
    int t = threadIdx.x;
    int r0 = (t >> 4) * 4, c0 = (t & 15) * 4;
    float acc[4][4] = {};
    for (int k = 0; k < 64; k++) {
        float b[4];
        #pragma unroll
        for (int j = 0; j < 4; j++) b[j] = right[k * 64 + c0 + j];
        #pragma unroll
        for (int i = 0; i < 4; i++) {
            float a = left[(r0 + i) * 64 + k];
            #pragma unroll
            for (int j = 0; j < 4; j++) acc[i][j] += a * b[j];
        }
    }
    for (int i = 0; i < 4; i++)
        for (int j = 0; j < 4; j++)
            out[(r0 + i) * 64 + c0 + j] = acc[i][j];
    if (t < 64) {
        float s = 0.f;
        for (int k = 0; k < 64; k++) s += lb[k] * right[k * 64 + t];
        ob[t] = s;
    }
}

// 4x4 micro-tile GEMM over a 64x64 tile; AT transposed in LDS (stride 68), W row-major in LDS.
__device__ __forceinline__ void gemm_tile(const float* AT, const float* W, float acc[4][4], int ty, int tx) {
    #pragma unroll
    for (int i = 0; i < 4; i++)
        #pragma unroll
        for (int j = 0; j < 4; j++) acc[i][j] = 0.f;
    #pragma unroll 4
    for (int k = 0; k < 64; k++) {
        const float4 a4 = *(const float4*)(AT + k * 68 + ty * 4);
        const float4 b4 = *(const float4*)(W + k * 64 + tx * 4);
        float a[4] = {a4.x, a4.y, a4.z, a4.w};
        float b[4] = {b4.x, b4.y, b4.z, b4.w};
        #pragma unroll
        for (int i = 0; i < 4; i++)
            #pragma unroll
            for (int j = 0; j < 4; j++) acc[i][j] += a[i] * b[j];
    }
}

// out1(f16) = X @ M1, out2(f32) = X @ M2 — layer 0: xW1 = x@Wx0, xA = x@A0
__global__ void k_gemm_two(const float* __restrict__ X, const float* __restrict__ M1,
                           const float* __restrict__ M2, __half* __restrict__ out1,
                           float* __restrict__ out2, int N) {
    __shared__ float XT[64 * 68];
    __shared__ float W[64 * 64];
    int t = threadIdx.x, ty = t >> 4, tx = t & 15;
    int base = blockIdx.x * 64;
    for (int q = 0; q < 4; q++) {
        int row = ty + q * 16;
        int gr = base + row;
        float4 v = make_float4(0.f, 0.f, 0.f, 0.f);
        if (gr < N) v = *(const float4*)(X + (size_t)gr * 64 + tx * 4);
        XT[(tx * 4 + 0) * 68 + row] = v.x;
        XT[(tx * 4 + 1) * 68 + row] = v.y;
        XT[(tx * 4 + 2) * 68 + row] = v.z;
        XT[(tx * 4 + 3) * 68 + row] = v.w;
    }
    for (int q = 0; q < 4; q++) ((float4*)W)[t + q * 256] = ((const float4*)M1)[t + q * 256];
    __syncthreads();
    float acc[4][4];
    gemm_tile(XT, W, acc, ty, tx);
    for (int i = 0; i < 4; i++) {
        int gr = base + ty * 4 + i;
        if (gr < N) {
            H4 o;
            o.h[0] = __float2half(acc[i][0]); o.h[1] = __float2half(acc[i][1]);
            o.h[2] = __float2half(acc[i][2]); o.h[3] = __float2half(acc[i][3]);
            *(H4*)(out1 + (size_t)gr * 64 + tx * 4) = o;
        }
    }
    __syncthreads();
    for (int q = 0; q < 4; q++) ((float4*)W)[t + q * 256] = ((const float4*)M2)[t + q * 256];
    __syncthreads();
    gemm_tile(XT, W, acc, ty, tx);
    for (int i = 0; i < 4; i++) {
        int gr = base + ty * 4 + i;
        if (gr < N) {
            float4 o = make_float4(acc[i][0], acc[i][1], acc[i][2], acc[i][3]);
            *(float4*)(out2 + (size_t)gr * 64 + tx * 4) = o;
        }
    }
}

__device__ __forceinline__ float edge_contrib(__half xw, const __half2* e8, const __half2* w, float b1) {
    __half2 sA = __hmul2(e8[0], w[0]);
    __half2 sB = __hmul2(e8[1], w[1]);
    sA = __hfma2(e8[2], w[2], sA);
    sB = __hfma2(e8[3], w[3], sB);
    sA = __hfma2(e8[4], w[4], sA);
    sB = __hfma2(e8[5], w[5], sB);
    sA = __hfma2(e8[6], w[6], sA);
    sB = __hfma2(e8[7], w[7], sB);
    __half2 s = __hadd2(sA, sB);
    float v = __half2float(xw) + b1 + __half2float(__low2half(s)) + __half2float(__high2half(s));
    return fmaxf(v, 0.f);
}

// Edge phase: one wave per destination node, lane = channel.
// Hsum[d][c] = sum over in-edges ReLU(xW1[s][c] + ea@We[:,c] + b1[c])
__global__ __launch_bounds__(256) void k_edge(
        const int* __restrict__ rowptr, const int* __restrict__ csr_src,
        const __half* __restrict__ eaPerm, const __half* __restrict__ xW1,
        const __half2* __restrict__ Wpack, const float* __restrict__ b1m,
        float* __restrict__ Hsum, int N) {
    int wid = __builtin_amdgcn_readfirstlane((blockIdx.x * blockDim.x + threadIdx.x) >> 6);
    int lane = threadIdx.x & 63;
    if (wid >= N) return;
    __half2 w[8];
    #pragma unroll
    for (int p = 0; p < 8; p++) w[p] = Wpack[p * 64 + lane];
    float b1 = b1m[lane];
    int beg = rowptr[wid], end = rowptr[wid + 1];
    float acc = 0.f;
    int j = beg;
    for (; j + 4 <= end; j += 4) {
        int s0 = csr_src[j + 0], s1 = csr_src[j + 1], s2 = csr_src[j + 2], s3 = csr_src[j + 3];
        __half x0 = xW1[(size_t)s0 * 64 + lane];
        __half x1 = xW1[(size_t)s1 * 64 + lane];
        __half x2 = xW1[(size_t)s2 * 64 + lane];
        __half x3 = xW1[(size_t)s3 * 64 + lane];
        float4 ebuf[8];
        const float4* ep = (const float4*)(eaPerm + (size_t)j * 16);
        #pragma unroll
        for (int q = 0; q < 8; q++) ebuf[q] = ep[q];
        acc += edge_contrib(x0, (const __half2*)&ebuf[0], w, b1);
        acc += edge_contrib(x1, (const __half2*)&ebuf[2], w, b1);
        acc += edge_contrib(x2, (const __half2*)&ebuf[4], w, b1);
        acc += edge_contrib(x3, (const __half2*)&ebuf[6], w, b1);
    }
    for (; j < end; j++) {
        int s0 = csr_src[j];
        __half x0 = xW1[(size_t)s0 * 64 + lane];
        float4 ebuf[2];
        const float4* ep = (const float4*)(eaPerm + (size_t)j * 16);
        ebuf[0] = ep[0]; ebuf[1] = ep[1];
        acc += edge_contrib(x0, (const __half2*)&ebuf[0], w, b1);
    }
    Hsum[(size_t)wid * 64 + lane] = acc;
}

// Node phase for layer l:
//   h = ReLU( Hsum@P + (1+eps)*xA + deg*pb + a_l )
//   pooled: hpool[batch[n]] += h
//   if has_next: out1(f16) = h@Q + qb (next xW1), out2(f32) = h@R + rb (next xA)
__global__ void k_node(const float* __restrict__ Hsum, const float* __restrict__ xA,
                       const int* __restrict__ deg, const int* __restrict__ batch,
                       const float* __restrict__ P, const float* __restrict__ pb,
                       const float* __restrict__ a_l, const float* __restrict__ epsp,
                       const float* __restrict__ Q, const float* __restrict__ qb,
                       __half* __restrict__ out1,
                       const float* __restrict__ R, const float* __restrict__ rb,
                       float* __restrict__ out2,
                       float* __restrict__ hpool_l, int N, int has_next) {
    __shared__ float AT[64 * 68];
    __shared__ float HT[64 * 68];
    __shared__ float W[64 * 64];
    int t = threadIdx.x, ty = t >> 4, tx = t & 15;
    int base = blockIdx.x * 64;
    for (int q = 0; q < 4; q++) {
        int row = ty + q * 16;
        int gr = base + row;
        float4 v = make_float4(0.f, 0.f, 0.f, 0.f);
        if (gr < N) v = *(const float4*)(Hsum + (size_t)gr * 64 + tx * 4);
        AT[(tx * 4 + 0) * 68 + row] = v.x;
        AT[(tx * 4 + 1) * 68 + row] = v.y;
        AT[(tx * 4 + 2) * 68 + row] = v.z;
        AT[(tx * 4 + 3) * 68 + row] = v.w;
    }
    for (int q = 0; q < 4; q++) ((float4*)W)[t + q * 256] = ((const float4*)P)[t + q * 256];
    __syncthreads();
    float acc[4][4];
    gemm_tile(AT, W, acc, ty, tx);
    float eps1 = 1.f + epsp[0];
    float4 pbv = *(const float4*)(pb + tx * 4);
    float4 av = *(const float4*)(a_l + tx * 4);
    float h[4][4];
    int gidx[4];
    for (int i = 0; i < 4; i++) {
        int gr = base + ty * 4 + i;
        float dg = 0.f;
        float4 xa = make_float4(0.f, 0.f, 0.f, 0.f);
        if (gr < N) {
            dg = (float)deg[gr];
            xa = *(const float4*)(xA + (size_t)gr * 64 + tx * 4);
            gidx[i] = batch[gr];
        } else {
            gidx[i] = -1;
        }
        h[i][0] = fmaxf(acc[i][0] + eps1 * xa.x + dg * pbv.x + av.x, 0.f);
        h[i][1] = fmaxf(acc[i][1] + eps1 * xa.y + dg * pbv.y + av.y, 0.f);
        h[i][2] = fmaxf(acc[i][2] + eps1 * xa.z + dg * pbv.z + av.z, 0.f);
        h[i][3] = fmaxf(acc[i][3] + eps1 * xa.w + dg * pbv.w + av.w, 0.f);
    }
    #pragma unroll
    for (int j = 0; j < 4; j++) {
        int i = 0;
        while (i < 4) {
            if (gidx[i] < 0) { i++; continue; }
            int g = gidx[i];
            float s = h[i][j];
            int k2 = i + 1;
            while (k2 < 4 && gidx[k2] == g) { s += h[k2][j]; k2++; }
            atomicAdd(&hpool_l[g * 64 + tx * 4 + j], s);
            i = k2;
        }
    }
    if (has_next) {
        for (int i = 0; i < 4; i++)
            for (int j = 0; j < 4; j++)
                HT[(tx * 4 + j) * 68 + ty * 4 + i] = h[i][j];
        __syncthreads();
        for (int q = 0; q < 4; q++) ((float4*)W)[t + q * 256] = ((const float4*)Q)[t + q * 256];
        __syncthreads();
        gemm_tile(HT, W, acc, ty, tx);
        float4 qbv = *(const float4*)(qb + tx * 4);
        for (int i = 0; i < 4; i++) {
            int gr = base + ty * 4 + i;
            if (gr < N) {
                H4 o;
                o.h[0] = __float2half(acc[i][0] + qbv.x);
                o.h[1] = __float2half(acc[i][1] + qbv.y);
                o.h[2] = __float2half(acc[i][2] + qbv.z);
                o.h[3] = __float2half(acc[i][3] + qbv.w);
                *(H4*)(out1 + (size_t)gr * 64 + tx * 4) = o;
            }
        }
        __syncthreads();
        for (int q = 0; q < 4; q++) ((float4*)W)[t + q * 256] = ((const float4*)R)[t + q * 256];
        __syncthreads();
        gemm_tile(HT, W, acc, ty, tx);
        float4 rbv = *(const float4*)(rb + tx * 4);
        for (int i = 0; i < 4; i++) {
            int gr = base + ty * 4 + i;
            if (gr < N) {
                float4 o = make_float4(acc[i][0] + rbv.x, acc[i][1] + rbv.y,
                                       acc[i][2] + rbv.z, acc[i][3] + rbv.w);
                *(float4*)(out2 + (size_t)gr * 64 + tx * 4) = o;
            }
        }
    }
}

// feats[g][l*64+c] = sum_k hpool[l][g][k]*nn1_w2[l][k][c] + cnt[g]*nn1_b2[l][c]
__global__ void k_pool_feats(const float* __restrict__ hpool, const int* __restrict__ cnt,
                             const float* __restrict__ nn1_w2, const float* __restrict__ nn1_b2,
                             float* __restrict__ feats, int G) {
    int l = blockIdx.x / G, g = blockIdx.x % G;
    int c = threadIdx.x;
    const float* hp = hpool + ((size_t)l * G + g) * 64;
    const float* B = nn1_w2 + l * 4096;
    float s = (float)cnt[g] * nn1_b2[l * 64 + c];
    for (int k = 0; k < 64; k++) s += hp[k] * B[k * 64 + c];
    feats[(size_t)g * (64 * NLAYERS) + l * 64 + c] = s;
}

// y[g] = ReLU(feats[g]@F1 + fb1) @ F2 + fb2
__global__ void k_final(const float* __restrict__ feats, const float* __restrict__ F1,
                        const float* __restrict__ fb1, const float* __restrict__ F2,
                        const float* __restrict__ fb2, float* __restrict__ out, int G) {
    int g = blockIdx.x;
    int c = threadIdx.x; // 320
    const float* f = feats + (size_t)g * 320;
    float s = fb1[c];
    for (int k = 0; k < 320; k++) s += f[k] * F1[k * 320 + c];
    s = fmaxf(s, 0.f);
    __shared__ float sh[320];
    sh[c] = s * F2[c];
    __syncthreads();
    if (c == 0) {
        float y = fb2[0];
        for (int k = 0; k < 320; k++) y += sh[k];
        out[g] = y;
    }
}

extern "C" void kernel_launch(void* const* d_in, const int* in_sizes, int n_in,
                              void* d_out, int out_size, void* d_ws, size_t ws_size,
                              hipStream_t stream) {
    const float* x        = (const float*)d_in[0];
    const int*   ei       = (const int*)d_in[1];
    const float* edge_attr= (const float*)d_in[2];
    const int*   batch    = (const int*)d_in[3];
    const float* nn2_w1   = (const float*)d_in[4];
    const float* nn2_b1   = (const float*)d_in[5];
    const float* nn2_w2   = (const float*)d_in[6];
    const float* nn2_b2   = (const float*)d_in[7];
    const float* nn1_w1   = (const float*)d_in[8];
    const float* nn1_b1   = (const float*)d_in[9];
    const float* nn1_w2   = (const float*)d_in[10];
    const float* nn1_b2   = (const float*)d_in[11];
    const float* fin_w1   = (const float*)d_in[12];
    const float* fin_b1   = (const float*)d_in[13];
    const float* fin_w2   = (const float*)d_in[14];
    const float* fin_b2   = (const float*)d_in[15];
    const float* eps      = (const float*)d_in[16];

    int N = in_sizes[0] / 64;
    int E = in_sizes[1] / 2;
    int G = out_size;

    char* p = (char*)d_ws;
    auto alloc = [&](size_t bytes) -> char* {
        char* r = p;
        p += (bytes + 255) & ~(size_t)255;
        return r;
    };
    int*    deg     = (int*)alloc((size_t)N * 4);
    int*    cnt     = (int*)alloc((size_t)G * 4);
    int*    rowptr  = (int*)alloc((size_t)(N + 1) * 4);
    int*    cursor  = (int*)alloc((size_t)(N + 1) * 4);
    int*    bsum    = (int*)alloc(256 * 4);
    int*    boff    = (int*)alloc(256 * 4);
    int*    csr_src = (int*)alloc((size_t)E * 4);
    __half* eaPerm  = (__half*)alloc((size_t)E * 16 * 2);
    __half* xW1     = (__half*)alloc((size_t)N * 64 * 2);
    float*  xA0     = (float*)alloc((size_t)N * 64 * 4);
    float*  xA1     = (float*)alloc((size_t)N * 64 * 4);
    float*  Hsum    = (float*)alloc((size_t)N * 64 * 4);
    float*  hpool   = (float*)alloc((size_t)NLAYERS * G * 64 * 4);
    float*  feats   = (float*)alloc((size_t)G * 320 * 4);
    float*  P       = (float*)alloc(5 * 4096 * 4);
    float*  pb      = (float*)alloc(5 * 64 * 4);
    float*  Q       = (float*)alloc(4 * 4096 * 4);
    float*  qb      = (float*)alloc(4 * 64 * 4);
    float*  R       = (float*)alloc(4 * 4096 * 4);
    float*  rb      = (float*)alloc(4 * 64 * 4);
    __half2* Wpack  = (__half2*)alloc(5 * 512 * 4);

    hipMemsetAsync(deg, 0, (size_t)N * 4, stream);
    hipMemsetAsync(cnt, 0, (size_t)G * 4, stream);
    hipMemsetAsync(hpool, 0, (size_t)NLAYERS * G * 64 * 4, stream);

    int Pblk = (N + 255) / 256;  // 196 <= 256
    k_deg_hist<<<1024, 256, 0, stream>>>(ei, E, deg);
    k_cnt_hist<<<256, 256, 0, stream>>>(batch, N, cnt);
    k_bsum<<<Pblk, 256, 0, stream>>>(deg, N, bsum);
    k_bscan<<<1, 256, 0, stream>>>(bsum, Pblk, boff, rowptr, N);
    k_rowptr<<<Pblk, 256, 0, stream>>>(deg, boff, N, rowptr, cursor);
    k_scatter<<<1024, 256, 0, stream>>>(ei, edge_attr, E, cursor, csr_src, eaPerm);
    k_wpack<<<5, 512, 0, stream>>>(nn2_w1, Wpack);
    k_precompute<<<13, 256, 0, stream>>>(nn2_w1, nn2_w2, nn2_b2, nn1_w1, nn1_w2, nn1_b2,
                                         P, pb, Q, qb, R, rb);

    int nb = (N + 63) / 64;
    k_gemm_two<<<nb, 256, 0, stream>>>(x, nn2_w1 /*Wx0*/, nn1_w1 /*A0*/, xW1, xA0, N);

    float* xA_cur = xA0;
    float* xA_nxt = xA1;
    int eblocks = (N + 3) / 4; // 4 waves/block, one wave per node
    for (int l = 0; l < NLAYERS; l++) {
        k_edge<<<eblocks, 256, 0, stream>>>(rowptr, csr_src, eaPerm, xW1,
                                            Wpack + l * 512, nn2_b1 + l * 64, Hsum, N);
        int has_next = (l < NLAYERS - 1) ? 1 : 0;
        k_node<<<nb, 256, 0, stream>>>(Hsum, xA_cur, deg, batch,
                                       P + l * 4096, pb + l * 64, nn1_b1 + l * 64, eps,
                                       Q + (has_next ? l : 0) * 4096, qb + (has_next ? l : 0) * 64, xW1,
                                       R + (has_next ? l : 0) * 4096, rb + (has_next ? l : 0) * 64, xA_nxt,
                                       hpool + (size_t)l * G * 64, N, has_next);
        float* tmp = xA_cur; xA_cur = xA_nxt; xA_nxt = tmp;
    }

    k_pool_feats<<<NLAYERS * G, 64, 0, stream>>>(hpool, cnt, nn1_w2, nn1_b2, feats, G);
    k_final<<<G, 320, 0, stream>>>(feats, fin_w1, fin_b1, fin_w2, fin_b2, (float*)d_out, G);
}